// Round 6
// baseline (238.371 us; speedup 1.0000x reference)
//
#include <hip/hip_runtime.h>
#include <math.h>

// nanoGPT Head: x[B,T,C] @ W{q,k,v}[C,H] -> causal softmax(QK^T/sqrt(H)) V
#define BB 8
#define TT 4096
#define CC 64
#define HH 128
#define NTH 256
#define XSTR 72        // proj x stride (bf16)
#define WSTR 72        // proj W stride (bf16)
// 128^-0.5 * log2(e): folded into Wq so S-scores are in log2 domain
#define QSCALE ((float)(0.08838834764831845 * 1.4426950408889634))

typedef __attribute__((ext_vector_type(8)))  short short8;    // 8 bf16 (MFMA A/B frag)
typedef __attribute__((ext_vector_type(4)))  float floatx4;   // 16x16 C/D frag
typedef __attribute__((ext_vector_type(16))) float floatx16;  // 32x32 C/D frag

__device__ __forceinline__ unsigned short f2bf(float f) {
    union { float f; unsigned int u; } un; un.f = f;
    unsigned int r = un.u + 0x7FFF + ((un.u >> 16) & 1);   // RNE
    return (unsigned short)(r >> 16);
}
// fast bf16 pair pack: round-half-up + v_perm (3 VALU ops)
__device__ __forceinline__ unsigned int pack2bf_fast(float a, float b) {
    union { float f; unsigned int u; } ua, ub; ua.f = a; ub.f = b;
    return __builtin_amdgcn_perm(ub.u + 0x8000u, ua.u + 0x8000u, 0x07060302u);
}
__device__ __forceinline__ float bflo(unsigned int u) {
    union { unsigned int u; float f; } x; x.u = u << 16; return x.f;
}
__device__ __forceinline__ float bfhi(unsigned int u) {
    union { unsigned int u; float f; } x; x.u = u & 0xffff0000u; return x.f;
}

// async global->LDS, 16B per lane; lds dest = wave-uniform base + lane*16
__device__ __forceinline__ void gl_lds16(const void* g, void* l) {
    __builtin_amdgcn_global_load_lds(
        (const __attribute__((address_space(1))) unsigned int*)g,
        (__attribute__((address_space(3))) unsigned int*)l, 16, 0, 0);
}

// ---------------- Kernel 0: one-time W fp32->bf16 in padded-LDS image ----------------
// Wbf[(mat*128 + h)*WSTR + c] = bf16(W[c][h] * (mat==0 ? QSCALE : 1))
// Block 0 additionally zeroes the 256 per-q-tile arrival counters (stream-ordered
// before flash_splitk each graph replay).
__global__ __launch_bounds__(NTH) void wconv(
    const float* __restrict__ Wq, const float* __restrict__ Wk, const float* __restrict__ Wv,
    unsigned short* __restrict__ Wbf, int* __restrict__ Cnt)
{
    const int tid = threadIdx.x;
    if (blockIdx.x == 0) Cnt[tid] = 0;               // 256 counters, one per (b,qt)
    const int id = blockIdx.x * NTH + tid;           // 0..24575
    const int mat = id >> 13;
    const int rem = id & 8191;
    const int h = rem & 127, c = rem >> 7;
    const float* W = mat == 0 ? Wq : (mat == 1 ? Wk : Wv);
    const float s = mat == 0 ? QSCALE : 1.0f;
    Wbf[(mat * HH + h) * WSTR + c] = f2bf(W[c * HH + h] * s);
}

// ---------------- Kernel 1: QKV projection via MFMA ----------------
// Q -> [B,T,H] row-major bf16.
// K -> fragment-tiled: 32-key half j (8192 B) @ (b*128+j)*8192 B
// V -> fragment-tiled (V^T), see round-0 comments.
__global__ __launch_bounds__(NTH) void qkv_mfma(
    const float* __restrict__ x, const unsigned short* __restrict__ Wbf,
    unsigned short* __restrict__ qb, unsigned short* __restrict__ Kf,
    unsigned short* __restrict__ Vf)
{
    __shared__ __align__(16) unsigned short xs[64 * XSTR];
    __shared__ __align__(16) unsigned short Wts[3 * HH * WSTR];

    const int tid  = threadIdx.x;
    const int w    = tid >> 6;
    const int lane = tid & 63;
    const int quad = lane >> 4;
    const int lr   = lane & 15;

    const int b    = blockIdx.x >> 6;
    const int kblk = blockIdx.x & 63;
    const int t0   = kblk * 64;
    const long long rbase = (long long)b * TT + t0;

    // stage pre-converted W (55296 B) via global_load_lds: zero VALU
    {
        const unsigned char* ws = (const unsigned char*)Wbf;
        unsigned char* wd = (unsigned char*)Wts;
#pragma unroll
        for (int it = 0; it < 14; ++it) {
            const int off = it * 4096 + tid * 16;
            if (off < 3 * HH * WSTR * 2)      // wave-uniform predicate (tail: waves 0,1 only)
                gl_lds16(ws + off, wd + off);
        }
    }
#pragma unroll
    for (int i = 0; i < 4; ++i) {
        const int idx = tid + i * NTH;
        const int r = idx >> 4, c4 = idx & 15;
        const float4 v = *(const float4*)(x + (rbase + r) * CC + c4 * 4);
        unsigned short tmp[4] = { f2bf(v.x), f2bf(v.y), f2bf(v.z), f2bf(v.w) };
        *(unsigned long long*)&xs[r * XSTR + c4 * 4] = *(unsigned long long*)tmp;
    }
    __syncthreads();   // drains gl_lds DMA (vmcnt) + ds_writes (lgkmcnt)

    const short8 bx0 = *(const short8*)&xs[(w * 16 + lr) * XSTR + quad * 8];
    const short8 bx1 = *(const short8*)&xs[(w * 16 + lr) * XSTR + 32 + quad * 8];

    // Q
    {
        const unsigned short* Wrow = Wts;
#pragma unroll
        for (int ht = 0; ht < 8; ++ht) {
            const short8 aw0 = *(const short8*)(Wrow + (ht * 16 + lr) * WSTR + quad * 8);
            const short8 aw1 = *(const short8*)(Wrow + (ht * 16 + lr) * WSTR + 32 + quad * 8);
            floatx4 acc = (floatx4)0.f;
            acc = __builtin_amdgcn_mfma_f32_16x16x32_bf16(aw0, bx0, acc, 0, 0, 0);
            acc = __builtin_amdgcn_mfma_f32_16x16x32_bf16(aw1, bx1, acc, 0, 0, 0);
            ushort4 st = { f2bf(acc[0]), f2bf(acc[1]), f2bf(acc[2]), f2bf(acc[3]) };
            *(ushort4*)(qb + (rbase + w * 16 + lr) * HH + ht * 16 + quad * 4) = st;
        }
    }
    // K fragment-tiled
    {
        const unsigned short* Wrow = Wts + 1 * HH * WSTR;
        const int khp = w >> 1;
        const int lqp = (w & 1) * 16 + lr;
        unsigned short* kdst = Kf + ((long long)((b * 64 + kblk) * 2 + khp)) * 4096
                             + ((quad >> 1) & 1) * 256 + lqp * 8 + (quad & 1) * 4;
#pragma unroll
        for (int ht = 0; ht < 8; ++ht) {
            const short8 aw0 = *(const short8*)(Wrow + (ht * 16 + lr) * WSTR + quad * 8);
            const short8 aw1 = *(const short8*)(Wrow + (ht * 16 + lr) * WSTR + 32 + quad * 8);
            floatx4 acc = (floatx4)0.f;
            acc = __builtin_amdgcn_mfma_f32_16x16x32_bf16(aw0, bx0, acc, 0, 0, 0);
            acc = __builtin_amdgcn_mfma_f32_16x16x32_bf16(aw1, bx1, acc, 0, 0, 0);
            ushort4 st = { f2bf(acc[0]), f2bf(acc[1]), f2bf(acc[2]), f2bf(acc[3]) };
            *(ushort4*)(kdst + ht * 512) = st;
        }
    }
    // V fragment-tiled
    {
        const unsigned short* Wrow = Wts + 2 * HH * WSTR;
        const int khv = w >> 1, ksv = w & 1, lsv = (quad >> 1) & 1;
        unsigned short* vdst = Vf + (long long)(b * 64 + kblk) * 8192 + khv * 4096
                             + ksv * 512 + lsv * 256 + (quad & 1) * 4;
#pragma unroll
        for (int htp = 0; htp < 8; ++htp) {
            const short8 bw0 = *(const short8*)(Wrow + (htp * 16 + lr) * WSTR + quad * 8);
            const short8 bw1 = *(const short8*)(Wrow + (htp * 16 + lr) * WSTR + 32 + quad * 8);
            floatx4 acc = (floatx4)0.f;
            acc = __builtin_amdgcn_mfma_f32_16x16x32_bf16(bx0, bw0, acc, 0, 0, 0);
            acc = __builtin_amdgcn_mfma_f32_16x16x32_bf16(bx1, bw1, acc, 0, 0, 0);
            ushort4 st = { f2bf(acc[0]), f2bf(acc[1]), f2bf(acc[2]), f2bf(acc[3]) };
            *(ushort4*)(vdst + (htp >> 1) * 1024 + ((htp & 1) * 16 + lr) * 8) = st;
        }
    }
}

// stage one 32-key tile (K 8KB + V 8KB) into LDS; 4 waves x 4KB each
__device__ __forceinline__ void dma_tile32(
    const unsigned char* __restrict__ Kj, const unsigned char* __restrict__ Vj,
    unsigned char* buf, int w, int lane)
{
    const unsigned char* src;
    unsigned char* dst;
    if (w < 2) { src = Kj + w * 4096 + lane * 16;        dst = buf + w * 4096; }
    else       { src = Vj + (w - 2) * 4096 + lane * 16;  dst = buf + 8192 + (w - 2) * 4096; }
#pragma unroll
    for (int i = 0; i < 4; ++i)
        gl_lds16(src + i * 1024, dst + i * 1024);
}

// ---------------- Kernel 2: split-K flash + fused last-arriver combine ----------------
// Compute body = EXACT round-0 structure (54.6/54.9 us verified; no setprio/permlane/tree-sum
// — that bundle cost +40 us of stall across two structures, rounds 2&4).
// After writing its partial, each block fences (device release) and bumps the q-tile counter;
// the 4th arriver fences (acquire) and combines the 4 L2/L3-hot partials into fp32 out —
// replaces the separate combine kernel (launch + cold re-read).
// 32x32x16: A[m=lane&31][k=(lane>>5)*8+j]; B[k][n=lane&31]; C/D: col=lane&31,
// row=(reg&3)+8*(reg>>2)+4*(lane>>5). No-max softmax (log2-domain scores via Wq).
__global__ __launch_bounds__(NTH, 3) void flash_splitk(
    const unsigned short* __restrict__ qb,
    const unsigned short* __restrict__ Kf,
    const unsigned short* __restrict__ Vf,
    unsigned short* __restrict__ Ob, float* __restrict__ Lb,
    int* __restrict__ Cnt, float* __restrict__ out)
{
    __shared__ __align__(16) unsigned char KV[2][16384];   // [buf][K 8KB | V 8KB]
    __shared__ int sArr;

    const int tid  = threadIdx.x;
    const int w    = tid >> 6;        // qh
    const int lane = tid & 63;
    const int lq   = lane & 31;
    const int ls   = lane >> 5;

    const int id = blockIdx.x;
    const int b  = id & 7;                        // XCD-pinned batch
    const int c  = (id >> 3) & 3;
    const int qt = 31 - (id >> 5);                // heavy q-tiles first
    const int len = qt + 1;                       // ntiles = 4*(qt+1), split exactly by 4
    const int lo  = c * len;
    const int hi  = lo + qt;                      // lo + len - 1

    const int q0 = qt * 128;
    const long long baset = (long long)b * TT;
    const unsigned char* Kbase = (const unsigned char*)Kf + (long long)b * 128 * 8192;
    const unsigned char* Vbase = (const unsigned char*)Vf + (long long)b * 128 * 8192;

    dma_tile32(Kbase + (long long)lo * 8192, Vbase + (long long)lo * 8192, KV[0], w, lane);

    // Q fragments: row q0 + w*32 + lq, d = st*16 + ls*8 + j
    short8 aq[8];
    {
        const unsigned short* qrp = qb + (baset + q0 + w * 32 + lq) * HH + ls * 8;
#pragma unroll
        for (int st = 0; st < 8; ++st)
            aq[st] = *(const short8*)(qrp + st * 16);
    }

    floatx16 o_acc[4];   // O^T partial: h = ht*32 + row(reg,ls), q = w*32+lq
#pragma unroll
    for (int ht = 0; ht < 4; ++ht) o_acc[ht] = (floatx16)0.f;
    float l_lane = 0.f;

    for (int j = lo; j <= hi; ++j) {
        const int cb = (j - lo) & 1;
        __syncthreads();   // compiler vmcnt(0) drains buf[cb] DMA; prior readers of buf[cb^1] done
        if (j < hi)        // prefetch next tile: in flight across this whole iteration
            dma_tile32(Kbase + (long long)(j + 1) * 8192, Vbase + (long long)(j + 1) * 8192,
                       KV[cb ^ 1], w, lane);

        const int D = q0 + w * 32 - j * 32;       // q_start - k_start (wave-uniform)
        if (D > -32) {
            const unsigned short* Kt = (const unsigned short*)&KV[cb][0];
            const unsigned short* Vt = (const unsigned short*)&KV[cb][8192];

            short8 kfr[8], vfr[8];
#pragma unroll
            for (int st = 0; st < 8; ++st)
                kfr[st] = *(const short8*)(Kt + st * 512 + lane * 8);
#pragma unroll
            for (int i = 0; i < 8; ++i)           // ht = i>>1, ks = i&1
                vfr[i] = *(const short8*)(Vt + (i >> 1) * 1024 + (i & 1) * 512 + lane * 8);

            // S^T = K Q^T
            floatx16 s_acc = (floatx16)0.f;
#pragma unroll
            for (int st = 0; st < 8; ++st)
                s_acc = __builtin_amdgcn_mfma_f32_32x32x16_bf16(kfr[st], aq[st], s_acc, 0, 0, 0);

            // p = exp2(s) (raw v_exp_f32), causal mask (kk <= lq + D), l accumulation
            float p[16];
            if (D < 31) {
#pragma unroll
                for (int reg = 0; reg < 16; ++reg) {
                    const int kk = (reg & 3) + 8 * (reg >> 2) + 4 * ls;
                    p[reg] = (kk <= lq + D) ? __builtin_amdgcn_exp2f(s_acc[reg]) : 0.f;
                }
            } else {
#pragma unroll
                for (int reg = 0; reg < 16; ++reg)
                    p[reg] = __builtin_amdgcn_exp2f(s_acc[reg]);
            }
#pragma unroll
            for (int reg = 0; reg < 16; ++reg) l_lane += p[reg];

            // P C-layout -> B-layout in-register (ls-pair exchange)
            unsigned int g[8], pg[8];
#pragma unroll
            for (int i = 0; i < 8; ++i) g[i] = pack2bf_fast(p[2 * i], p[2 * i + 1]);
#pragma unroll
            for (int i = 0; i < 8; ++i) pg[i] = __shfl_xor((int)g[i], 32);
            short8 bp[2];
#pragma unroll
            for (int ks = 0; ks < 2; ++ks) {
                union { short8 s; unsigned int u[4]; } fr;
                const int bs = ks * 4;
                if (ls == 0) {
                    fr.u[0] = g[bs];      fr.u[1] = g[bs + 1];
                    fr.u[2] = pg[bs];     fr.u[3] = pg[bs + 1];
                } else {
                    fr.u[0] = pg[bs + 2]; fr.u[1] = pg[bs + 3];
                    fr.u[2] = g[bs + 2];  fr.u[3] = g[bs + 3];
                }
                bp[ks] = fr.s;
            }

            // O^T += V^T P^T
#pragma unroll
            for (int ht = 0; ht < 4; ++ht) {
                o_acc[ht] = __builtin_amdgcn_mfma_f32_32x32x16_bf16(vfr[ht * 2 + 0], bp[0], o_acc[ht], 0, 0, 0);
                o_acc[ht] = __builtin_amdgcn_mfma_f32_32x32x16_bf16(vfr[ht * 2 + 1], bp[1], o_acc[ht], 0, 0, 0);
            }
        }
    }

    // ---- epilogue: wave-local; fold ls halves of l, write raw partial O + l ----
    const int tile = b * 32 + qt;
    const int pid = (tile << 2) + c;
    const float l2 = l_lane + __shfl_xor(l_lane, 32);
    if (lane < 32) Lb[pid * 128 + w * 32 + lq] = l2;

    unsigned short* od = Ob + (long long)pid * 16384 + (w * 32 + lq) * HH;
#pragma unroll
    for (int ht = 0; ht < 4; ++ht)
#pragma unroll
        for (int rg = 0; rg < 4; ++rg) {
            uint2 st;
            st.x = pack2bf_fast(o_acc[ht][rg * 4 + 0], o_acc[ht][rg * 4 + 1]);
            st.y = pack2bf_fast(o_acc[ht][rg * 4 + 2], o_acc[ht][rg * 4 + 3]);
            *(uint2*)(od + ht * 32 + rg * 8 + 4 * ls) = st;
        }

    // ---- fused combine: last of the 4 chunk-blocks reduces this q-tile ----
    __syncthreads();                       // all threads' partial stores drained (vmcnt0)
    if (tid == 0) {
        __threadfence();                   // release: partials visible device-wide
        sArr = atomicAdd(&Cnt[tile], 1);
    }
    __syncthreads();
    if (sArr == 3) {
        __threadfence();                   // acquire: no stale lines for foreign partials
        const int pid0 = tile << 2;
        const int hg = tid & 3;
#pragma unroll
        for (int pass = 0; pass < 2; ++pass) {
            const int q = pass * 64 + (tid >> 2);    // 0..127 within tile
            float acc[32];
#pragma unroll
            for (int i = 0; i < 32; ++i) acc[i] = 0.f;
            float ltot = 0.f;
#pragma unroll
            for (int cc = 0; cc < 4; ++cc) {
                ltot += Lb[(pid0 + cc) * 128 + q];
                const uint4* src = (const uint4*)(Ob + (long long)(pid0 + cc) * 16384 + q * HH + hg * 32);
#pragma unroll
                for (int g = 0; g < 4; ++g) {
                    const uint4 d = src[g];
                    acc[g * 8 + 0] += bflo(d.x); acc[g * 8 + 1] += bfhi(d.x);
                    acc[g * 8 + 2] += bflo(d.y); acc[g * 8 + 3] += bfhi(d.y);
                    acc[g * 8 + 4] += bflo(d.z); acc[g * 8 + 5] += bfhi(d.z);
                    acc[g * 8 + 6] += bflo(d.w); acc[g * 8 + 7] += bfhi(d.w);
                }
            }
            const float inv = 1.f / ltot;
            float* op = out + (baset + q0 + q) * HH + hg * 32;
#pragma unroll
            for (int g = 0; g < 8; ++g) {
                float4 st = make_float4(acc[g * 4 + 0] * inv, acc[g * 4 + 1] * inv,
                                        acc[g * 4 + 2] * inv, acc[g * 4 + 3] * inv);
                *(float4*)(op + g * 4) = st;
            }
        }
    }
}

extern "C" void kernel_launch(void* const* d_in, const int* in_sizes, int n_in,
                              void* d_out, int out_size, void* d_ws, size_t ws_size,
                              hipStream_t stream)
{
    const float* x  = (const float*)d_in[0];
    const float* Wq = (const float*)d_in[1];
    const float* Wk = (const float*)d_in[2];
    const float* Wv = (const float*)d_in[3];
    float* out = (float*)d_out;

    const long long n = (long long)BB * TT * HH;   // 4,194,304
    unsigned short* qb = (unsigned short*)d_ws;
    unsigned short* Kf = qb + n;
    unsigned short* Vf = Kf + n;
    unsigned short* Ob = Vf + n;                   // 1024 * 16384 bf16 = 33.5 MB
    float*          Lb = (float*)(Ob + (long long)1024 * 16384);  // 1024*128 fp32
    unsigned short* Wbf = (unsigned short*)(Lb + 1024 * 128);     // 3*128*72 bf16
    int*            Cnt = (int*)(Wbf + 3 * HH * WSTR);            // 256 arrival counters

    wconv<<<96, NTH, 0, stream>>>(Wq, Wk, Wv, Wbf, Cnt);
    qkv_mfma<<<BB * (TT / 64), NTH, 0, stream>>>(x, Wbf, qb, Kf, Vf);
    flash_splitk<<<1024, NTH, 0, stream>>>(qb, Kf, Vf, Ob, Lb, Cnt, out);
}

// Round 7
// 138.939 us; speedup vs baseline: 1.7157x; 1.7157x over previous
//
#include <hip/hip_runtime.h>
#include <math.h>

// nanoGPT Head: x[B,T,C] @ W{q,k,v}[C,H] -> causal softmax(QK^T/sqrt(H)) V
#define BB 8
#define TT 4096
#define CC 64
#define HH 128
#define NTH 256
#define XSTR 72        // proj x stride (bf16)
#define WSTR 72        // proj W stride (bf16)
// 128^-0.5 * log2(e): folded into Wq so S-scores are in log2 domain
#define QSCALE ((float)(0.08838834764831845 * 1.4426950408889634))

typedef __attribute__((ext_vector_type(8)))  short short8;    // 8 bf16 (MFMA A/B frag)
typedef __attribute__((ext_vector_type(4)))  float floatx4;   // 16x16 C/D frag
typedef __attribute__((ext_vector_type(16))) float floatx16;  // 32x32 C/D frag

__device__ __forceinline__ unsigned short f2bf(float f) {
    union { float f; unsigned int u; } un; un.f = f;
    unsigned int r = un.u + 0x7FFF + ((un.u >> 16) & 1);   // RNE
    return (unsigned short)(r >> 16);
}
// fast bf16 pair pack: round-half-up + v_perm (3 VALU ops)
__device__ __forceinline__ unsigned int pack2bf_fast(float a, float b) {
    union { float f; unsigned int u; } ua, ub; ua.f = a; ub.f = b;
    return __builtin_amdgcn_perm(ub.u + 0x8000u, ua.u + 0x8000u, 0x07060302u);
}
__device__ __forceinline__ float bflo(unsigned int u) {
    union { unsigned int u; float f; } x; x.u = u << 16; return x.f;
}
__device__ __forceinline__ float bfhi(unsigned int u) {
    union { unsigned int u; float f; } x; x.u = u & 0xffff0000u; return x.f;
}

// async global->LDS, 16B per lane; lds dest = wave-uniform base + lane*16
__device__ __forceinline__ void gl_lds16(const void* g, void* l) {
    __builtin_amdgcn_global_load_lds(
        (const __attribute__((address_space(1))) unsigned int*)g,
        (__attribute__((address_space(3))) unsigned int*)l, 16, 0, 0);
}

// ---------------- Kernel 0: one-time W fp32->bf16 in padded-LDS image ----------------
// Wbf[(mat*128 + h)*WSTR + c] = bf16(W[c][h] * (mat==0 ? QSCALE : 1))
__global__ __launch_bounds__(NTH) void wconv(
    const float* __restrict__ Wq, const float* __restrict__ Wk, const float* __restrict__ Wv,
    unsigned short* __restrict__ Wbf)
{
    const int id = blockIdx.x * NTH + threadIdx.x;   // 0..24575
    const int mat = id >> 13;
    const int rem = id & 8191;
    const int h = rem & 127, c = rem >> 7;
    const float* W = mat == 0 ? Wq : (mat == 1 ? Wk : Wv);
    const float s = mat == 0 ? QSCALE : 1.0f;
    Wbf[(mat * HH + h) * WSTR + c] = f2bf(W[c * HH + h] * s);
}

// ---------------- Kernel 1: QKV projection via MFMA ----------------
// Q -> [B,T,H] row-major bf16.
// K -> fragment-tiled: 32-key half j (8192 B) @ (b*128+j)*8192 B
// V -> fragment-tiled (V^T), see round-0 comments.
__global__ __launch_bounds__(NTH) void qkv_mfma(
    const float* __restrict__ x, const unsigned short* __restrict__ Wbf,
    unsigned short* __restrict__ qb, unsigned short* __restrict__ Kf,
    unsigned short* __restrict__ Vf)
{
    __shared__ __align__(16) unsigned short xs[64 * XSTR];
    __shared__ __align__(16) unsigned short Wts[3 * HH * WSTR];

    const int tid  = threadIdx.x;
    const int w    = tid >> 6;
    const int lane = tid & 63;
    const int quad = lane >> 4;
    const int lr   = lane & 15;

    const int b    = blockIdx.x >> 6;
    const int kblk = blockIdx.x & 63;
    const int t0   = kblk * 64;
    const long long rbase = (long long)b * TT + t0;

    // stage pre-converted W (55296 B) via global_load_lds: zero VALU
    {
        const unsigned char* ws = (const unsigned char*)Wbf;
        unsigned char* wd = (unsigned char*)Wts;
#pragma unroll
        for (int it = 0; it < 14; ++it) {
            const int off = it * 4096 + tid * 16;
            if (off < 3 * HH * WSTR * 2)      // wave-uniform predicate (tail: waves 0,1 only)
                gl_lds16(ws + off, wd + off);
        }
    }
#pragma unroll
    for (int i = 0; i < 4; ++i) {
        const int idx = tid + i * NTH;
        const int r = idx >> 4, c4 = idx & 15;
        const float4 v = *(const float4*)(x + (rbase + r) * CC + c4 * 4);
        unsigned short tmp[4] = { f2bf(v.x), f2bf(v.y), f2bf(v.z), f2bf(v.w) };
        *(unsigned long long*)&xs[r * XSTR + c4 * 4] = *(unsigned long long*)tmp;
    }
    __syncthreads();   // drains gl_lds DMA (vmcnt) + ds_writes (lgkmcnt)

    const short8 bx0 = *(const short8*)&xs[(w * 16 + lr) * XSTR + quad * 8];
    const short8 bx1 = *(const short8*)&xs[(w * 16 + lr) * XSTR + 32 + quad * 8];

    // Q
    {
        const unsigned short* Wrow = Wts;
#pragma unroll
        for (int ht = 0; ht < 8; ++ht) {
            const short8 aw0 = *(const short8*)(Wrow + (ht * 16 + lr) * WSTR + quad * 8);
            const short8 aw1 = *(const short8*)(Wrow + (ht * 16 + lr) * WSTR + 32 + quad * 8);
            floatx4 acc = (floatx4)0.f;
            acc = __builtin_amdgcn_mfma_f32_16x16x32_bf16(aw0, bx0, acc, 0, 0, 0);
            acc = __builtin_amdgcn_mfma_f32_16x16x32_bf16(aw1, bx1, acc, 0, 0, 0);
            ushort4 st = { f2bf(acc[0]), f2bf(acc[1]), f2bf(acc[2]), f2bf(acc[3]) };
            *(ushort4*)(qb + (rbase + w * 16 + lr) * HH + ht * 16 + quad * 4) = st;
        }
    }
    // K fragment-tiled
    {
        const unsigned short* Wrow = Wts + 1 * HH * WSTR;
        const int khp = w >> 1;
        const int lqp = (w & 1) * 16 + lr;
        unsigned short* kdst = Kf + ((long long)((b * 64 + kblk) * 2 + khp)) * 4096
                             + ((quad >> 1) & 1) * 256 + lqp * 8 + (quad & 1) * 4;
#pragma unroll
        for (int ht = 0; ht < 8; ++ht) {
            const short8 aw0 = *(const short8*)(Wrow + (ht * 16 + lr) * WSTR + quad * 8);
            const short8 aw1 = *(const short8*)(Wrow + (ht * 16 + lr) * WSTR + 32 + quad * 8);
            floatx4 acc = (floatx4)0.f;
            acc = __builtin_amdgcn_mfma_f32_16x16x32_bf16(aw0, bx0, acc, 0, 0, 0);
            acc = __builtin_amdgcn_mfma_f32_16x16x32_bf16(aw1, bx1, acc, 0, 0, 0);
            ushort4 st = { f2bf(acc[0]), f2bf(acc[1]), f2bf(acc[2]), f2bf(acc[3]) };
            *(ushort4*)(kdst + ht * 512) = st;
        }
    }
    // V fragment-tiled
    {
        const unsigned short* Wrow = Wts + 2 * HH * WSTR;
        const int khv = w >> 1, ksv = w & 1, lsv = (quad >> 1) & 1;
        unsigned short* vdst = Vf + (long long)(b * 64 + kblk) * 8192 + khv * 4096
                             + ksv * 512 + lsv * 256 + (quad & 1) * 4;
#pragma unroll
        for (int htp = 0; htp < 8; ++htp) {
            const short8 bw0 = *(const short8*)(Wrow + (htp * 16 + lr) * WSTR + quad * 8);
            const short8 bw1 = *(const short8*)(Wrow + (htp * 16 + lr) * WSTR + 32 + quad * 8);
            floatx4 acc = (floatx4)0.f;
            acc = __builtin_amdgcn_mfma_f32_16x16x32_bf16(bx0, bw0, acc, 0, 0, 0);
            acc = __builtin_amdgcn_mfma_f32_16x16x32_bf16(bx1, bw1, acc, 0, 0, 0);
            ushort4 st = { f2bf(acc[0]), f2bf(acc[1]), f2bf(acc[2]), f2bf(acc[3]) };
            *(ushort4*)(vdst + (htp >> 1) * 1024 + ((htp & 1) * 16 + lr) * 8) = st;
        }
    }
}

// stage one 32-key tile (K 8KB + V 8KB) into LDS; 4 waves x 4KB each
__device__ __forceinline__ void dma_tile32(
    const unsigned char* __restrict__ Kj, const unsigned char* __restrict__ Vj,
    unsigned char* buf, int w, int lane)
{
    const unsigned char* src;
    unsigned char* dst;
    if (w < 2) { src = Kj + w * 4096 + lane * 16;        dst = buf + w * 4096; }
    else       { src = Vj + (w - 2) * 4096 + lane * 16;  dst = buf + 8192 + (w - 2) * 4096; }
#pragma unroll
    for (int i = 0; i < 4; ++i)
        gl_lds16(src + i * 1024, dst + i * 1024);
}

// ---------------- Kernel 2: split-K flash — EXACT round-0/round-5 structure and body ----------------
// (54.9 us verified, round 5). NO setprio/permlane/tree-sum (rounds 2&4: +40us stall) and
// NO fences/fused combine (round 6: L2 writeback storms, flash 55->192us).
// 32x32x16: A[m=lane&31][k=(lane>>5)*8+j]; B[k][n=lane&31]; C/D: col=lane&31,
// row=(reg&3)+8*(reg>>2)+4*(lane>>5). No-max softmax (log2-domain scores via Wq).
__global__ __launch_bounds__(NTH, 3) void flash_splitk(
    const unsigned short* __restrict__ qb,
    const unsigned short* __restrict__ Kf,
    const unsigned short* __restrict__ Vf,
    unsigned short* __restrict__ Ob, float* __restrict__ Lb)
{
    __shared__ __align__(16) unsigned char KV[2][16384];   // [buf][K 8KB | V 8KB]

    const int tid  = threadIdx.x;
    const int w    = tid >> 6;        // qh
    const int lane = tid & 63;
    const int lq   = lane & 31;
    const int ls   = lane >> 5;

    const int id = blockIdx.x;
    const int b  = id & 7;                        // XCD-pinned batch
    const int c  = (id >> 3) & 3;
    const int qt = 31 - (id >> 5);                // heavy q-tiles first
    const int len = qt + 1;                       // ntiles = 4*(qt+1), split exactly by 4
    const int lo  = c * len;
    const int hi  = lo + qt;                      // lo + len - 1

    const int q0 = qt * 128;
    const long long baset = (long long)b * TT;
    const unsigned char* Kbase = (const unsigned char*)Kf + (long long)b * 128 * 8192;
    const unsigned char* Vbase = (const unsigned char*)Vf + (long long)b * 128 * 8192;

    dma_tile32(Kbase + (long long)lo * 8192, Vbase + (long long)lo * 8192, KV[0], w, lane);

    // Q fragments: row q0 + w*32 + lq, d = st*16 + ls*8 + j
    short8 aq[8];
    {
        const unsigned short* qrp = qb + (baset + q0 + w * 32 + lq) * HH + ls * 8;
#pragma unroll
        for (int st = 0; st < 8; ++st)
            aq[st] = *(const short8*)(qrp + st * 16);
    }

    floatx16 o_acc[4];   // O^T partial: h = ht*32 + row(reg,ls), q = w*32+lq
#pragma unroll
    for (int ht = 0; ht < 4; ++ht) o_acc[ht] = (floatx16)0.f;
    float l_lane = 0.f;

    for (int j = lo; j <= hi; ++j) {
        const int cb = (j - lo) & 1;
        __syncthreads();   // compiler vmcnt(0) drains buf[cb] DMA; prior readers of buf[cb^1] done
        if (j < hi)        // prefetch next tile: in flight across this whole iteration
            dma_tile32(Kbase + (long long)(j + 1) * 8192, Vbase + (long long)(j + 1) * 8192,
                       KV[cb ^ 1], w, lane);

        const int D = q0 + w * 32 - j * 32;       // q_start - k_start (wave-uniform)
        if (D > -32) {
            const unsigned short* Kt = (const unsigned short*)&KV[cb][0];
            const unsigned short* Vt = (const unsigned short*)&KV[cb][8192];

            short8 kfr[8], vfr[8];
#pragma unroll
            for (int st = 0; st < 8; ++st)
                kfr[st] = *(const short8*)(Kt + st * 512 + lane * 8);
#pragma unroll
            for (int i = 0; i < 8; ++i)           // ht = i>>1, ks = i&1
                vfr[i] = *(const short8*)(Vt + (i >> 1) * 1024 + (i & 1) * 512 + lane * 8);

            // S^T = K Q^T
            floatx16 s_acc = (floatx16)0.f;
#pragma unroll
            for (int st = 0; st < 8; ++st)
                s_acc = __builtin_amdgcn_mfma_f32_32x32x16_bf16(kfr[st], aq[st], s_acc, 0, 0, 0);

            // p = exp2(s) (raw v_exp_f32), causal mask (kk <= lq + D), l accumulation
            float p[16];
            if (D < 31) {
#pragma unroll
                for (int reg = 0; reg < 16; ++reg) {
                    const int kk = (reg & 3) + 8 * (reg >> 2) + 4 * ls;
                    p[reg] = (kk <= lq + D) ? __builtin_amdgcn_exp2f(s_acc[reg]) : 0.f;
                }
            } else {
#pragma unroll
                for (int reg = 0; reg < 16; ++reg)
                    p[reg] = __builtin_amdgcn_exp2f(s_acc[reg]);
            }
#pragma unroll
            for (int reg = 0; reg < 16; ++reg) l_lane += p[reg];

            // P C-layout -> B-layout in-register (ls-pair exchange)
            unsigned int g[8], pg[8];
#pragma unroll
            for (int i = 0; i < 8; ++i) g[i] = pack2bf_fast(p[2 * i], p[2 * i + 1]);
#pragma unroll
            for (int i = 0; i < 8; ++i) pg[i] = __shfl_xor((int)g[i], 32);
            short8 bp[2];
#pragma unroll
            for (int ks = 0; ks < 2; ++ks) {
                union { short8 s; unsigned int u[4]; } fr;
                const int bs = ks * 4;
                if (ls == 0) {
                    fr.u[0] = g[bs];      fr.u[1] = g[bs + 1];
                    fr.u[2] = pg[bs];     fr.u[3] = pg[bs + 1];
                } else {
                    fr.u[0] = pg[bs + 2]; fr.u[1] = pg[bs + 3];
                    fr.u[2] = g[bs + 2];  fr.u[3] = g[bs + 3];
                }
                bp[ks] = fr.s;
            }

            // O^T += V^T P^T
#pragma unroll
            for (int ht = 0; ht < 4; ++ht) {
                o_acc[ht] = __builtin_amdgcn_mfma_f32_32x32x16_bf16(vfr[ht * 2 + 0], bp[0], o_acc[ht], 0, 0, 0);
                o_acc[ht] = __builtin_amdgcn_mfma_f32_32x32x16_bf16(vfr[ht * 2 + 1], bp[1], o_acc[ht], 0, 0, 0);
            }
        }
    }

    // ---- epilogue: wave-local; fold ls halves of l, write raw partial O + l ----
    const int pid = ((b * 32 + qt) << 2) + c;
    const float l2 = l_lane + __shfl_xor(l_lane, 32);
    if (lane < 32) Lb[pid * 128 + w * 32 + lq] = l2;

    unsigned short* od = Ob + (long long)pid * 16384 + (w * 32 + lq) * HH;
#pragma unroll
    for (int ht = 0; ht < 4; ++ht)
#pragma unroll
        for (int rg = 0; rg < 4; ++rg) {
            uint2 st;
            st.x = pack2bf_fast(o_acc[ht][rg * 4 + 0], o_acc[ht][rg * 4 + 1]);
            st.y = pack2bf_fast(o_acc[ht][rg * 4 + 2], o_acc[ht][rg * 4 + 3]);
            *(uint2*)(od + ht * 32 + rg * 8 + 4 * ls) = st;
        }
}

// ---------------- Kernel 3: combine 4 chunk partials, divide by l — TLP redesign ----------------
// Round-6 forensics: old 512-block combine measured ~40 us (vs ~9 us traffic floor) —
// latency-bound at 25% occupancy with register-serialized load batches.
// New: 2048 blocks (b x 32 q-tiles x 8 row-slices), thread = (q-row, 8-h slice):
// 4 independent 16B loads + acc[8]; 8 blocks/CU -> 32 waves/CU, wave accesses 1KB/2KB contiguous.
__global__ __launch_bounds__(NTH) void combine(
    const unsigned short* __restrict__ Ob, const float* __restrict__ Lb,
    float* __restrict__ out)
{
    const int id = blockIdx.x;                 // 0..2047
    const int b = id & 7;
    const int rest = id >> 3;                  // 0..255
    const int qt = rest >> 3;                  // 0..31
    const int eighth = rest & 7;
    const int tid = threadIdx.x;
    const int q = eighth * 16 + (tid >> 4);    // 0..127 within tile
    const int hg = tid & 15;                   // h0 = hg*8
    const int pid0 = ((b * 32 + qt) << 2);

    float acc[8];
#pragma unroll
    for (int i = 0; i < 8; ++i) acc[i] = 0.f;
    float ltot = 0.f;

#pragma unroll
    for (int cc = 0; cc < 4; ++cc) {
        ltot += Lb[(pid0 + cc) * 128 + q];
        const uint4 d = *(const uint4*)(Ob + (long long)(pid0 + cc) * 16384 + q * HH + hg * 8);
        acc[0] += bflo(d.x); acc[1] += bfhi(d.x);
        acc[2] += bflo(d.y); acc[3] += bfhi(d.y);
        acc[4] += bflo(d.z); acc[5] += bfhi(d.z);
        acc[6] += bflo(d.w); acc[7] += bfhi(d.w);
    }
    const float inv = 1.f / ltot;
    float* op = out + ((long long)b * TT + qt * 128 + q) * HH + hg * 8;
    float4 s0 = make_float4(acc[0] * inv, acc[1] * inv, acc[2] * inv, acc[3] * inv);
    float4 s1 = make_float4(acc[4] * inv, acc[5] * inv, acc[6] * inv, acc[7] * inv);
    *(float4*)(op) = s0;
    *(float4*)(op + 4) = s1;
}

extern "C" void kernel_launch(void* const* d_in, const int* in_sizes, int n_in,
                              void* d_out, int out_size, void* d_ws, size_t ws_size,
                              hipStream_t stream)
{
    const float* x  = (const float*)d_in[0];
    const float* Wq = (const float*)d_in[1];
    const float* Wk = (const float*)d_in[2];
    const float* Wv = (const float*)d_in[3];
    float* out = (float*)d_out;

    const long long n = (long long)BB * TT * HH;   // 4,194,304
    unsigned short* qb = (unsigned short*)d_ws;
    unsigned short* Kf = qb + n;
    unsigned short* Vf = Kf + n;
    unsigned short* Ob = Vf + n;                   // 1024 * 16384 bf16 = 33.5 MB
    float*          Lb = (float*)(Ob + (long long)1024 * 16384);  // 1024*128 fp32
    unsigned short* Wbf = (unsigned short*)(Lb + 1024 * 128);     // 3*128*72 bf16

    wconv<<<96, NTH, 0, stream>>>(Wq, Wk, Wv, Wbf);
    qkv_mfma<<<BB * (TT / 64), NTH, 0, stream>>>(x, Wbf, qb, Kf, Vf);
    flash_splitk<<<1024, NTH, 0, stream>>>(qb, Kf, Vf, Ob, Lb);
    combine<<<BB * 32 * 8, NTH, 0, stream>>>(Ob, Lb, out);
}

// Round 8
// 136.964 us; speedup vs baseline: 1.7404x; 1.0144x over previous
//
#include <hip/hip_runtime.h>
#include <math.h>

// nanoGPT Head: x[B,T,C] @ W{q,k,v}[C,H] -> causal softmax(QK^T/sqrt(H)) V
#define BB 8
#define TT 4096
#define CC 64
#define HH 128
#define NTH 256
#define XSTR 72        // proj x stride (bf16)
#define WSTR 72        // proj W stride (bf16)
// 128^-0.5 * log2(e): folded into Wq so S-scores are in log2 domain
#define QSCALE ((float)(0.08838834764831845 * 1.4426950408889634))

typedef __attribute__((ext_vector_type(8)))  short short8;    // 8 bf16 (MFMA A/B frag)
typedef __attribute__((ext_vector_type(4)))  float floatx4;   // 16x16 C/D frag
typedef __attribute__((ext_vector_type(16))) float floatx16;  // 32x32 C/D frag

__device__ __forceinline__ unsigned short f2bf(float f) {
    union { float f; unsigned int u; } un; un.f = f;
    unsigned int r = un.u + 0x7FFF + ((un.u >> 16) & 1);   // RNE
    return (unsigned short)(r >> 16);
}
// fast bf16 pair pack: round-half-up + v_perm (3 VALU ops)
__device__ __forceinline__ unsigned int pack2bf_fast(float a, float b) {
    union { float f; unsigned int u; } ua, ub; ua.f = a; ub.f = b;
    return __builtin_amdgcn_perm(ub.u + 0x8000u, ua.u + 0x8000u, 0x07060302u);
}
__device__ __forceinline__ float bflo(unsigned int u) {
    union { unsigned int u; float f; } x; x.u = u << 16; return x.f;
}
__device__ __forceinline__ float bfhi(unsigned int u) {
    union { unsigned int u; float f; } x; x.u = u & 0xffff0000u; return x.f;
}

// async global->LDS, 16B per lane; lds dest = wave-uniform base + lane*16
__device__ __forceinline__ void gl_lds16(const void* g, void* l) {
    __builtin_amdgcn_global_load_lds(
        (const __attribute__((address_space(1))) unsigned int*)g,
        (__attribute__((address_space(3))) unsigned int*)l, 16, 0, 0);
}

// ---------------- Kernel 0: one-time W fp32->bf16 in padded-LDS image ----------------
// Wbf[(mat*128 + h)*WSTR + c] = bf16(W[c][h] * (mat==0 ? QSCALE : 1))
__global__ __launch_bounds__(NTH) void wconv(
    const float* __restrict__ Wq, const float* __restrict__ Wk, const float* __restrict__ Wv,
    unsigned short* __restrict__ Wbf)
{
    const int id = blockIdx.x * NTH + threadIdx.x;   // 0..24575
    const int mat = id >> 13;
    const int rem = id & 8191;
    const int h = rem & 127, c = rem >> 7;
    const float* W = mat == 0 ? Wq : (mat == 1 ? Wk : Wv);
    const float s = mat == 0 ? QSCALE : 1.0f;
    Wbf[(mat * HH + h) * WSTR + c] = f2bf(W[c * HH + h] * s);
}

// ---------------- Kernel 1: QKV projection via MFMA ----------------
// XCD-MATCHED DECODE (round 8): b = id&7, kblk = id>>3, so XCD(id%8) == b — batch b's
// Q/K/V are written into XCD b's L2, the same XCD flash_splitk (b = id&7) reads them on.
// Old decode (b = id>>6) scattered batch b's K/V across all 8 XCD L2s -> flash's
// heavy-first critical-path blocks first-touched every tile from HBM (~1us/iter).
// Q -> [B,T,H] row-major bf16.
// K -> fragment-tiled: 32-key half j (8192 B) @ (b*128+j)*8192 B
// V -> fragment-tiled (V^T), see round-0 comments.
__global__ __launch_bounds__(NTH) void qkv_mfma(
    const float* __restrict__ x, const unsigned short* __restrict__ Wbf,
    unsigned short* __restrict__ qb, unsigned short* __restrict__ Kf,
    unsigned short* __restrict__ Vf)
{
    __shared__ __align__(16) unsigned short xs[64 * XSTR];
    __shared__ __align__(16) unsigned short Wts[3 * HH * WSTR];

    const int tid  = threadIdx.x;
    const int w    = tid >> 6;
    const int lane = tid & 63;
    const int quad = lane >> 4;
    const int lr   = lane & 15;

    const int b    = blockIdx.x & 7;          // XCD-pinned batch (matches flash)
    const int kblk = blockIdx.x >> 3;         // 0..63
    const int t0   = kblk * 64;
    const long long rbase = (long long)b * TT + t0;

    // stage pre-converted W (55296 B) via global_load_lds: zero VALU
    {
        const unsigned char* ws = (const unsigned char*)Wbf;
        unsigned char* wd = (unsigned char*)Wts;
#pragma unroll
        for (int it = 0; it < 14; ++it) {
            const int off = it * 4096 + tid * 16;
            if (off < 3 * HH * WSTR * 2)      // wave-uniform predicate (tail: waves 0,1 only)
                gl_lds16(ws + off, wd + off);
        }
    }
#pragma unroll
    for (int i = 0; i < 4; ++i) {
        const int idx = tid + i * NTH;
        const int r = idx >> 4, c4 = idx & 15;
        const float4 v = *(const float4*)(x + (rbase + r) * CC + c4 * 4);
        unsigned short tmp[4] = { f2bf(v.x), f2bf(v.y), f2bf(v.z), f2bf(v.w) };
        *(unsigned long long*)&xs[r * XSTR + c4 * 4] = *(unsigned long long*)tmp;
    }
    __syncthreads();   // drains gl_lds DMA (vmcnt) + ds_writes (lgkmcnt)

    const short8 bx0 = *(const short8*)&xs[(w * 16 + lr) * XSTR + quad * 8];
    const short8 bx1 = *(const short8*)&xs[(w * 16 + lr) * XSTR + 32 + quad * 8];

    // Q
    {
        const unsigned short* Wrow = Wts;
#pragma unroll
        for (int ht = 0; ht < 8; ++ht) {
            const short8 aw0 = *(const short8*)(Wrow + (ht * 16 + lr) * WSTR + quad * 8);
            const short8 aw1 = *(const short8*)(Wrow + (ht * 16 + lr) * WSTR + 32 + quad * 8);
            floatx4 acc = (floatx4)0.f;
            acc = __builtin_amdgcn_mfma_f32_16x16x32_bf16(aw0, bx0, acc, 0, 0, 0);
            acc = __builtin_amdgcn_mfma_f32_16x16x32_bf16(aw1, bx1, acc, 0, 0, 0);
            ushort4 st = { f2bf(acc[0]), f2bf(acc[1]), f2bf(acc[2]), f2bf(acc[3]) };
            *(ushort4*)(qb + (rbase + w * 16 + lr) * HH + ht * 16 + quad * 4) = st;
        }
    }
    // K fragment-tiled
    {
        const unsigned short* Wrow = Wts + 1 * HH * WSTR;
        const int khp = w >> 1;
        const int lqp = (w & 1) * 16 + lr;
        unsigned short* kdst = Kf + ((long long)((b * 64 + kblk) * 2 + khp)) * 4096
                             + ((quad >> 1) & 1) * 256 + lqp * 8 + (quad & 1) * 4;
#pragma unroll
        for (int ht = 0; ht < 8; ++ht) {
            const short8 aw0 = *(const short8*)(Wrow + (ht * 16 + lr) * WSTR + quad * 8);
            const short8 aw1 = *(const short8*)(Wrow + (ht * 16 + lr) * WSTR + 32 + quad * 8);
            floatx4 acc = (floatx4)0.f;
            acc = __builtin_amdgcn_mfma_f32_16x16x32_bf16(aw0, bx0, acc, 0, 0, 0);
            acc = __builtin_amdgcn_mfma_f32_16x16x32_bf16(aw1, bx1, acc, 0, 0, 0);
            ushort4 st = { f2bf(acc[0]), f2bf(acc[1]), f2bf(acc[2]), f2bf(acc[3]) };
            *(ushort4*)(kdst + ht * 512) = st;
        }
    }
    // V fragment-tiled
    {
        const unsigned short* Wrow = Wts + 2 * HH * WSTR;
        const int khv = w >> 1, ksv = w & 1, lsv = (quad >> 1) & 1;
        unsigned short* vdst = Vf + (long long)(b * 64 + kblk) * 8192 + khv * 4096
                             + ksv * 512 + lsv * 256 + (quad & 1) * 4;
#pragma unroll
        for (int htp = 0; htp < 8; ++htp) {
            const short8 bw0 = *(const short8*)(Wrow + (htp * 16 + lr) * WSTR + quad * 8);
            const short8 bw1 = *(const short8*)(Wrow + (htp * 16 + lr) * WSTR + 32 + quad * 8);
            floatx4 acc = (floatx4)0.f;
            acc = __builtin_amdgcn_mfma_f32_16x16x32_bf16(bx0, bw0, acc, 0, 0, 0);
            acc = __builtin_amdgcn_mfma_f32_16x16x32_bf16(bx1, bw1, acc, 0, 0, 0);
            ushort4 st = { f2bf(acc[0]), f2bf(acc[1]), f2bf(acc[2]), f2bf(acc[3]) };
            *(ushort4*)(vdst + (htp >> 1) * 1024 + ((htp & 1) * 16 + lr) * 8) = st;
        }
    }
}

// stage one 32-key tile (K 8KB + V 8KB) into LDS; 4 waves x 4KB each
__device__ __forceinline__ void dma_tile32(
    const unsigned char* __restrict__ Kj, const unsigned char* __restrict__ Vj,
    unsigned char* buf, int w, int lane)
{
    const unsigned char* src;
    unsigned char* dst;
    if (w < 2) { src = Kj + w * 4096 + lane * 16;        dst = buf + w * 4096; }
    else       { src = Vj + (w - 2) * 4096 + lane * 16;  dst = buf + 8192 + (w - 2) * 4096; }
#pragma unroll
    for (int i = 0; i < 4; ++i)
        gl_lds16(src + i * 1024, dst + i * 1024);
}

// ---------------- Kernel 2: split-K flash — EXACT round-0/round-5/round-7 structure ----------------
// (53.4 us verified, round 7). NO setprio/permlane/tree-sum (rounds 2&4: +40us stall);
// NO fences/fused combine (round 6: L2 writeback storms).
// 32x32x16: A[m=lane&31][k=(lane>>5)*8+j]; B[k][n=lane&31]; C/D: col=lane&31,
// row=(reg&3)+8*(reg>>2)+4*(lane>>5). No-max softmax (log2-domain scores via Wq).
__global__ __launch_bounds__(NTH, 3) void flash_splitk(
    const unsigned short* __restrict__ qb,
    const unsigned short* __restrict__ Kf,
    const unsigned short* __restrict__ Vf,
    unsigned short* __restrict__ Ob, float* __restrict__ Lb)
{
    __shared__ __align__(16) unsigned char KV[2][16384];   // [buf][K 8KB | V 8KB]

    const int tid  = threadIdx.x;
    const int w    = tid >> 6;        // qh
    const int lane = tid & 63;
    const int lq   = lane & 31;
    const int ls   = lane >> 5;

    const int id = blockIdx.x;
    const int b  = id & 7;                        // XCD-pinned batch
    const int c  = (id >> 3) & 3;
    const int qt = 31 - (id >> 5);                // heavy q-tiles first
    const int len = qt + 1;                       // ntiles = 4*(qt+1), split exactly by 4
    const int lo  = c * len;
    const int hi  = lo + qt;                      // lo + len - 1

    const int q0 = qt * 128;
    const long long baset = (long long)b * TT;
    const unsigned char* Kbase = (const unsigned char*)Kf + (long long)b * 128 * 8192;
    const unsigned char* Vbase = (const unsigned char*)Vf + (long long)b * 128 * 8192;

    dma_tile32(Kbase + (long long)lo * 8192, Vbase + (long long)lo * 8192, KV[0], w, lane);

    // Q fragments: row q0 + w*32 + lq, d = st*16 + ls*8 + j
    short8 aq[8];
    {
        const unsigned short* qrp = qb + (baset + q0 + w * 32 + lq) * HH + ls * 8;
#pragma unroll
        for (int st = 0; st < 8; ++st)
            aq[st] = *(const short8*)(qrp + st * 16);
    }

    floatx16 o_acc[4];   // O^T partial: h = ht*32 + row(reg,ls), q = w*32+lq
#pragma unroll
    for (int ht = 0; ht < 4; ++ht) o_acc[ht] = (floatx16)0.f;
    float l_lane = 0.f;

    for (int j = lo; j <= hi; ++j) {
        const int cb = (j - lo) & 1;
        __syncthreads();   // compiler vmcnt(0) drains buf[cb] DMA; prior readers of buf[cb^1] done
        if (j < hi)        // prefetch next tile: in flight across this whole iteration
            dma_tile32(Kbase + (long long)(j + 1) * 8192, Vbase + (long long)(j + 1) * 8192,
                       KV[cb ^ 1], w, lane);

        const int D = q0 + w * 32 - j * 32;       // q_start - k_start (wave-uniform)
        if (D > -32) {
            const unsigned short* Kt = (const unsigned short*)&KV[cb][0];
            const unsigned short* Vt = (const unsigned short*)&KV[cb][8192];

            short8 kfr[8], vfr[8];
#pragma unroll
            for (int st = 0; st < 8; ++st)
                kfr[st] = *(const short8*)(Kt + st * 512 + lane * 8);
#pragma unroll
            for (int i = 0; i < 8; ++i)           // ht = i>>1, ks = i&1
                vfr[i] = *(const short8*)(Vt + (i >> 1) * 1024 + (i & 1) * 512 + lane * 8);

            // S^T = K Q^T
            floatx16 s_acc = (floatx16)0.f;
#pragma unroll
            for (int st = 0; st < 8; ++st)
                s_acc = __builtin_amdgcn_mfma_f32_32x32x16_bf16(kfr[st], aq[st], s_acc, 0, 0, 0);

            // p = exp2(s) (raw v_exp_f32), causal mask (kk <= lq + D), l accumulation
            float p[16];
            if (D < 31) {
#pragma unroll
                for (int reg = 0; reg < 16; ++reg) {
                    const int kk = (reg & 3) + 8 * (reg >> 2) + 4 * ls;
                    p[reg] = (kk <= lq + D) ? __builtin_amdgcn_exp2f(s_acc[reg]) : 0.f;
                }
            } else {
#pragma unroll
                for (int reg = 0; reg < 16; ++reg)
                    p[reg] = __builtin_amdgcn_exp2f(s_acc[reg]);
            }
#pragma unroll
            for (int reg = 0; reg < 16; ++reg) l_lane += p[reg];

            // P C-layout -> B-layout in-register (ls-pair exchange)
            unsigned int g[8], pg[8];
#pragma unroll
            for (int i = 0; i < 8; ++i) g[i] = pack2bf_fast(p[2 * i], p[2 * i + 1]);
#pragma unroll
            for (int i = 0; i < 8; ++i) pg[i] = __shfl_xor((int)g[i], 32);
            short8 bp[2];
#pragma unroll
            for (int ks = 0; ks < 2; ++ks) {
                union { short8 s; unsigned int u[4]; } fr;
                const int bs = ks * 4;
                if (ls == 0) {
                    fr.u[0] = g[bs];      fr.u[1] = g[bs + 1];
                    fr.u[2] = pg[bs];     fr.u[3] = pg[bs + 1];
                } else {
                    fr.u[0] = pg[bs + 2]; fr.u[1] = pg[bs + 3];
                    fr.u[2] = g[bs + 2];  fr.u[3] = g[bs + 3];
                }
                bp[ks] = fr.s;
            }

            // O^T += V^T P^T
#pragma unroll
            for (int ht = 0; ht < 4; ++ht) {
                o_acc[ht] = __builtin_amdgcn_mfma_f32_32x32x16_bf16(vfr[ht * 2 + 0], bp[0], o_acc[ht], 0, 0, 0);
                o_acc[ht] = __builtin_amdgcn_mfma_f32_32x32x16_bf16(vfr[ht * 2 + 1], bp[1], o_acc[ht], 0, 0, 0);
            }
        }
    }

    // ---- epilogue: wave-local; fold ls halves of l, write raw partial O + l ----
    const int pid = ((b * 32 + qt) << 2) + c;
    const float l2 = l_lane + __shfl_xor(l_lane, 32);
    if (lane < 32) Lb[pid * 128 + w * 32 + lq] = l2;

    unsigned short* od = Ob + (long long)pid * 16384 + (w * 32 + lq) * HH;
#pragma unroll
    for (int ht = 0; ht < 4; ++ht)
#pragma unroll
        for (int rg = 0; rg < 4; ++rg) {
            uint2 st;
            st.x = pack2bf_fast(o_acc[ht][rg * 4 + 0], o_acc[ht][rg * 4 + 1]);
            st.y = pack2bf_fast(o_acc[ht][rg * 4 + 2], o_acc[ht][rg * 4 + 3]);
            *(uint2*)(od + ht * 32 + rg * 8 + 4 * ls) = st;
        }
}

// ---------------- Kernel 3: combine 4 chunk partials, divide by l (round-7 TLP version) ----------------
// 2048 blocks (b x 32 q-tiles x 8 row-slices); thread = (q-row, 8-h slice).
__global__ __launch_bounds__(NTH) void combine(
    const unsigned short* __restrict__ Ob, const float* __restrict__ Lb,
    float* __restrict__ out)
{
    const int id = blockIdx.x;                 // 0..2047
    const int b = id & 7;
    const int rest = id >> 3;                  // 0..255
    const int qt = rest >> 3;                  // 0..31
    const int eighth = rest & 7;
    const int tid = threadIdx.x;
    const int q = eighth * 16 + (tid >> 4);    // 0..127 within tile
    const int hg = tid & 15;                   // h0 = hg*8
    const int pid0 = ((b * 32 + qt) << 2);

    float acc[8];
#pragma unroll
    for (int i = 0; i < 8; ++i) acc[i] = 0.f;
    float ltot = 0.f;

#pragma unroll
    for (int cc = 0; cc < 4; ++cc) {
        ltot += Lb[(pid0 + cc) * 128 + q];
        const uint4 d = *(const uint4*)(Ob + (long long)(pid0 + cc) * 16384 + q * HH + hg * 8);
        acc[0] += bflo(d.x); acc[1] += bfhi(d.x);
        acc[2] += bflo(d.y); acc[3] += bfhi(d.y);
        acc[4] += bflo(d.z); acc[5] += bfhi(d.z);
        acc[6] += bflo(d.w); acc[7] += bfhi(d.w);
    }
    const float inv = 1.f / ltot;
    float* op = out + ((long long)b * TT + qt * 128 + q) * HH + hg * 8;
    float4 s0 = make_float4(acc[0] * inv, acc[1] * inv, acc[2] * inv, acc[3] * inv);
    float4 s1 = make_float4(acc[4] * inv, acc[5] * inv, acc[6] * inv, acc[7] * inv);
    *(float4*)(op) = s0;
    *(float4*)(op + 4) = s1;
}

extern "C" void kernel_launch(void* const* d_in, const int* in_sizes, int n_in,
                              void* d_out, int out_size, void* d_ws, size_t ws_size,
                              hipStream_t stream)
{
    const float* x  = (const float*)d_in[0];
    const float* Wq = (const float*)d_in[1];
    const float* Wk = (const float*)d_in[2];
    const float* Wv = (const float*)d_in[3];
    float* out = (float*)d_out;

    const long long n = (long long)BB * TT * HH;   // 4,194,304
    unsigned short* qb = (unsigned short*)d_ws;
    unsigned short* Kf = qb + n;
    unsigned short* Vf = Kf + n;
    unsigned short* Ob = Vf + n;                   // 1024 * 16384 bf16 = 33.5 MB
    float*          Lb = (float*)(Ob + (long long)1024 * 16384);  // 1024*128 fp32
    unsigned short* Wbf = (unsigned short*)(Lb + 1024 * 128);     // 3*128*72 bf16

    wconv<<<96, NTH, 0, stream>>>(Wq, Wk, Wv, Wbf);
    qkv_mfma<<<BB * (TT / 64), NTH, 0, stream>>>(x, Wbf, qb, Kf, Vf);
    flash_splitk<<<1024, NTH, 0, stream>>>(qb, Kf, Vf, Ob, Lb);
    combine<<<BB * 32 * 8, NTH, 0, stream>>>(Ob, Lb, out);
}